// Round 10
// baseline (259.044 us; speedup 1.0000x reference)
//
#include <hip/hip_runtime.h>
#include <math.h>

// ---------------------------------------------------------------------------
// MS-SSIM + MSE loss, (16,3,512,512) f32, 5 pyramid levels.
// R10: scalar 4-field column streaming, one unified kernel for all levels.
//  - 4 FIR fields: conv(a), conv(b), conv(a^2+b^2), conv(ab); per-col
//    products computed ONCE at stage time, stored in LDS as (a,b),(ab,sq).
//  - 2-slot LDS double buffer, runtime parity addr (rr&1); unroll-11 inner
//    keeps FIR register renaming static; t-loop of 4 outside.
//  - depth-2 global load pipeline (rows rr+1, rr+2 in registers).
//  - no inline fences; compiler-counted waitcnts (validated in R9).
//  - MSE rides load path (L0, rows<32); 2x2 pool reads both LDS slots.
// Per-wave partials, final 1-block f64 reduce. No atomics.
// ---------------------------------------------------------------------------

#define NPLANES 48

struct GaussW { float g[11]; };

typedef float v2f __attribute__((ext_vector_type(2)));

// ws float offsets: pyramids + per-WAVE partial areas
#define PYR2_OFF  4177920
#define P_L0      8355840   // 6144 pairs
#define P_L1      8368128   // 1536 pairs
#define P_L2      8371200   // 384 pairs
#define P_L3      8371968   // 96 pairs
#define P_L4      8372160   // 48 pairs
#define P_MSE     8372256   // 6144 singles

#define C1F 1.0e-4f
#define C2F 9.0e-4f

// ---------------------------------------------------------------------------
template <int LOGW, int DO_MSE, int DO_POOL>
__global__ __launch_bounds__(256, 4) void ssim_s4(
    const float* __restrict__ x1, const float* __restrict__ x2, GaussW gw,
    float* __restrict__ partials, float* __restrict__ msep,
    float* __restrict__ d1, float* __restrict__ d2)
{
  constexpr int W = 1 << LOGW;
  constexpr int Ho = W - 10;
  constexpr int CS = (Ho + 63) >> 6;   // 64-col strips (strips tile W)
  constexpr int RS = (Ho + 31) >> 5;   // 32-out-row bands
  constexpr int PW = RS * CS;
  constexpr int W2 = W >> 1;

  // [wave][slot][kind: 0=(a,b) 1=(ab,a^2+b^2)][col]; 9728 B total
  __shared__ v2f rbuf[4][2][2][76];

  const int tid = threadIdx.x;
  const int wid = tid >> 6, lane = tid & 63;
  const int gwid = blockIdx.x * 4 + wid;
  const int plane = gwid / PW;
  const int rem = gwid - plane * PW;
  const int rsi = rem / CS;
  const int csi = rem - rsi * CS;

  const int gr0 = 32 * rsi;
  const int c0 = 64 * csi;
  const int cb = c0 + lane;
  const int ROWS = (W - gr0 > 42) ? 42 : (W - gr0);  // >= 32 always
  const bool cok = cb < W;                     // W=32: lanes >=32 idle
  const bool hok = (csi < CS - 1) && (lane < 10);
  const bool hwr = lane < 10;                  // always write halo (zeros ok)

  const size_t pb = (size_t)plane * W * W;
  const float* q1 = x1 + pb + (size_t)gr0 * W + cb;
  const float* q2 = x2 + pb + (size_t)gr0 * W + cb;

  v2f (*rb)[2][76] = rbuf[wid];

  float mse = 0.f, sacc = 0.f, cacc = 0.f;

  // 4-field transposed FIR: f*[10] emits out row (rr-10)
  float f1[11], f2[11], f3[11], f4[11];
#pragma unroll
  for (int j = 0; j < 11; ++j) { f1[j] = 0.f; f2[j] = 0.f; f3[j] = 0.f; f4[j] = 0.f; }

#define LOADR(R, a, b, ah, bh)                                          \
  {                                                                     \
    a = 0.f; b = 0.f; ah = 0.f; bh = 0.f;                               \
    if ((R) < ROWS) {                                                   \
      size_t ro = (size_t)(R) * W;                                      \
      if (cok) { a = q1[ro]; b = q2[ro]; }                              \
      if (hok) { ah = q1[ro + 64]; bh = q2[ro + 64]; }                  \
      if (DO_MSE && (R) < 32) {                                         \
        float d_ = a - b;                                               \
        mse = fmaf(d_, d_, mse);                                        \
      }                                                                 \
    }                                                                   \
  }

#define STAGER(SL, a, b, ah, bh)                                        \
  {                                                                     \
    rb[SL][0][lane] = (v2f){a, b};                                      \
    rb[SL][1][lane] = (v2f){a * b, fmaf(a, a, b * b)};                  \
    if (hwr) {                                                          \
      rb[SL][0][64 + lane] = (v2f){ah, bh};                             \
      rb[SL][1][64 + lane] = (v2f){ah * bh, fmaf(ah, ah, bh * bh)};     \
    }                                                                   \
  }

  // prologue: row 0 staged in slot 0; rows 1,2 in register pipeline
  {
    float a, b, ah, bh;
    LOADR(0, a, b, ah, bh)
    STAGER(0, a, b, ah, bh)
  }
  float aA, bA, ahA, bhA, aB, bB, ahB, bhB;
  LOADR(1, aA, bA, ahA, bhA)
  LOADR(2, aB, bB, ahB, bhB)

  for (int t = 0; t < 4; ++t) {
#pragma unroll
    for (int u = 0; u < 11; ++u) {
      const int rr = 11 * t + u;
      // tail-only skip: once rr>=ROWS nothing later matters (FIR unused)
      if (rr < ROWS) {
        const int sc = rr & 1, sn = sc ^ 1;

        // stage row rr+1 (loaded 2 iters ago); advance register pipeline
        if (rr + 1 < ROWS) STAGER(sn, aA, bA, ahA, bhA)
        aA = aB; bA = bB; ahA = ahB; bhA = bhB;
        LOADR(rr + 3, aB, bB, ahB, bhB)

        // ---- H-pass: 4 fields, 11 taps, reads (a,b) and (ab,sq) pairs ----
        const v2f* rab = &rb[sc][0][lane];
        const v2f* rpq = &rb[sc][1][lane];
        float s1 = 0.f, s2 = 0.f, s3 = 0.f, s4 = 0.f;
#pragma unroll
        for (int k = 0; k < 11; ++k) {
          v2f ab = rab[k], pq = rpq[k];
          float g = gw.g[k];
          s1 = fmaf(g, ab.x, s1);
          s2 = fmaf(g, ab.y, s2);
          s4 = fmaf(g, pq.x, s4);
          s3 = fmaf(g, pq.y, s3);
        }

        // ---- V-pass: shift-accumulate (renamed over unroll-11) ----
#pragma unroll
        for (int j = 10; j >= 1; --j) {
          f1[j] = fmaf(gw.g[j], s1, f1[j - 1]);
          f2[j] = fmaf(gw.g[j], s2, f2[j - 1]);
          f3[j] = fmaf(gw.g[j], s3, f3[j - 1]);
          f4[j] = fmaf(gw.g[j], s4, f4[j - 1]);
        }
        f1[0] = gw.g[0] * s1;
        f2[0] = gw.g[0] * s2;
        f3[0] = gw.g[0] * s3;
        f4[0] = gw.g[0] * s4;

        // ---- emit SSIM/CS for out row (gr0 + rr - 10) ----
        if (rr >= 10) {
          float m1 = f1[10], m2 = f2[10], e3 = f3[10], e4 = f4[10];
          float m12 = m1 * m2;
          float msq = fmaf(m1, m1, m2 * m2);
          float v1 = 2.f * (e4 - m12) + C2F;
          float vv2 = (e3 - msq) + C2F;
          float csv = v1 * __builtin_amdgcn_rcpf(vv2);
          cacc += csv;
          sacc += csv * (2.f * m12 + C1F) *
                  __builtin_amdgcn_rcpf(msq + C1F);
        }

        // ---- fused 2x2 avgpool: pair (rr, rr+1), both slots resident ----
        if (DO_POOL && ((rr & 1) == 0) && rr < 32 && lane < 32) {
          v2f A0 = rb[sc][0][2 * lane], A1 = rb[sc][0][2 * lane + 1];
          v2f B0 = rb[sn][0][2 * lane], B1 = rb[sn][0][2 * lane + 1];
          int prow = 16 * rsi + (rr >> 1);
          size_t ob = (size_t)plane * W2 * W2 + (size_t)prow * W2 +
                      (c0 >> 1) + lane;
          d1[ob] = 0.25f * ((A0.x + A1.x) + (B0.x + B1.x));
          d2[ob] = 0.25f * ((A0.y + A1.y) + (B0.y + B1.y));
        }
      }
    }
  }
#undef LOADR
#undef STAGER

  // column-validity mask (kills cols >= Ho, incl. cok=false lanes)
  {
    float mk = (cb < Ho) ? 1.f : 0.f;
    sacc *= mk;
    cacc *= mk;
  }

  // ---- wave reduce + per-wave partial write ----
#pragma unroll
  for (int off = 32; off; off >>= 1) {
    sacc += __shfl_down(sacc, off);
    cacc += __shfl_down(cacc, off);
    if (DO_MSE) mse += __shfl_down(mse, off);
  }
  if (lane == 0) {
    partials[2 * gwid] = sacc;
    partials[2 * gwid + 1] = cacc;
    if (DO_MSE) msep[gwid] = mse;
  }
}

// ---------------------------------------------------------------------------
__global__ __launch_bounds__(256) void final_kernel(
    const float* __restrict__ ws, float* __restrict__ out)
{
  __shared__ double sred[2][4];
  __shared__ double fin[11];  // ssim[5], cs[5], mse
  const int tid = threadIdx.x;
  const int offs[5] = {P_L0, P_L1, P_L2, P_L3, P_L4};
  const int cnts[5] = {6144, 1536, 384, 96, 48};

  for (int l = 0; l < 5; ++l) {
    double s0 = 0.0, s1 = 0.0;
    for (int i = tid; i < cnts[l]; i += 256) {
      s0 += (double)ws[offs[l] + 2 * i];
      s1 += (double)ws[offs[l] + 2 * i + 1];
    }
#pragma unroll
    for (int off = 32; off; off >>= 1) {
      s0 += __shfl_down(s0, off);
      s1 += __shfl_down(s1, off);
    }
    if ((tid & 63) == 0) { sred[0][tid >> 6] = s0; sred[1][tid >> 6] = s1; }
    __syncthreads();
    if (tid == 0) {
      double aa = 0.0, bb = 0.0;
      for (int i = 0; i < 4; ++i) { aa += sred[0][i]; bb += sred[1][i]; }
      fin[l] = aa;
      fin[5 + l] = bb;
    }
    __syncthreads();
  }

  {
    double s0 = 0.0;
    for (int i = tid; i < 6144; i += 256) s0 += (double)ws[P_MSE + i];
#pragma unroll
    for (int off = 32; off; off >>= 1) s0 += __shfl_down(s0, off);
    if ((tid & 63) == 0) sred[0][tid >> 6] = s0;
    __syncthreads();
    if (tid == 0) {
      double aa = 0.0;
      for (int i = 0; i < 4; ++i) aa += sred[0][i];
      fin[10] = aa;
    }
    __syncthreads();
  }

  if (tid == 0) {
    const double wts[5] = {0.0448, 0.2856, 0.3001, 0.2363, 0.1333};
    const double dims[5] = {502.0, 246.0, 118.0, 54.0, 22.0};
    double mssim[5], mcs[5];
    for (int l = 0; l < 5; ++l) {
      double n = 48.0 * dims[l] * dims[l];
      mssim[l] = fin[l] / n;
      mcs[l] = fin[5 + l] / n;
    }
    // literal pytorch_msssim translation: prod(pow1[:-1] * pow2[-1])
    double p2last = pow(mssim[4], wts[4]);
    double prod = 1.0;
    for (int i = 0; i < 4; ++i) prod *= pow(mcs[i], wts[i]) * p2last;
    double msssim = prod;
    double mse = fin[10] / 12582912.0;
    out[0] = (float)(mse - msssim + 1.0);
    out[1] = (float)msssim;
  }
}

// ---------------------------------------------------------------------------
extern "C" void kernel_launch(void* const* d_in, const int* in_sizes, int n_in,
                              void* d_out, int out_size, void* d_ws, size_t ws_size,
                              hipStream_t stream)
{
  const float* rec = (const float*)d_in[0];   // reconst
  const float* orig = (const float*)d_in[1];  // original
  float* ws = (float*)d_ws;
  float* out = (float*)d_out;

  GaussW gw;
  {
    double g[11], s = 0.0;
    for (int i = 0; i < 11; ++i) {
      double x = (double)i - 5.0;
      g[i] = exp(-(x * x) / 4.5);
      s += g[i];
    }
    for (int i = 0; i < 11; ++i) gw.g[i] = (float)(g[i] / s);
  }

  // pyramid pointers
  float* A1 = ws + 0;
  float* A2 = ws + 3145728;
  float* A3 = ws + 3932160;
  float* A4 = ws + 4128768;
  float* B1 = ws + PYR2_OFF;
  float* B2 = ws + PYR2_OFF + 3145728;
  float* B3 = ws + PYR2_OFF + 3932160;
  float* B4 = ws + PYR2_OFF + 4128768;

  // waves = 48 * RS * CS; blocks = waves / 4
  ssim_s4<9, 1, 1><<<dim3(1536), 256, 0, stream>>>(
      orig, rec, gw, ws + P_L0, ws + P_MSE, A1, B1);   // 16 bands x 8 strips
  ssim_s4<8, 0, 1><<<dim3(384), 256, 0, stream>>>(
      A1, B1, gw, ws + P_L1, nullptr, A2, B2);         // 8 x 4
  ssim_s4<7, 0, 1><<<dim3(96), 256, 0, stream>>>(
      A2, B2, gw, ws + P_L2, nullptr, A3, B3);         // 4 x 2
  ssim_s4<6, 0, 1><<<dim3(24), 256, 0, stream>>>(
      A3, B3, gw, ws + P_L3, nullptr, A4, B4);         // 2 x 1
  ssim_s4<5, 0, 0><<<dim3(12), 256, 0, stream>>>(
      A4, B4, gw, ws + P_L4, nullptr, nullptr, nullptr); // 1 x 1

  final_kernel<<<dim3(1), dim3(256), 0, stream>>>(ws, out);
}